// Round 5
// baseline (452.946 us; speedup 1.0000x reference)
//
#include <hip/hip_runtime.h>
#include <hip/hip_bf16.h>
#include <type_traits>

#define LF 64
#define NBAGS 5
#define BROWS 2048
#define OUTC 320
#define KC 2048
#define MT_BLOCK 128               // 4 waves x 32 rows
#define NMT (BROWS / MT_BLOCK)     // 16

#define WS_SUMS_BYTES 65536
#define WP_BYTES 23068672ull       // 2816 tiles * 8192 B
#define PART_OFF (WS_SUMS_BYTES + WP_BYTES)
#define NCHUNKS 90                 // bags 1..4: 30 + 1 + 49 + 10
#define PART_BYTES ((size_t)NCHUNKS * BROWS * LF * 4)

typedef __attribute__((ext_vector_type(8))) short short8;
typedef __attribute__((ext_vector_type(4))) float f32x4;

struct BagArgs {
    const int*   A[NBAGS];
    const float* W[NBAGS];
    int K[NBAGS];
    int cstart[NBAGS + 1];   // KC-chunk prefix, bags 1..4
    int tstart[NBAGS + 1];   // 64-k tile prefix, all bags
};

__device__ __forceinline__ unsigned short f2bf(float f) {
    unsigned u = __float_as_uint(f);
    u += 0x7FFFu + ((u >> 16) & 1u);   // round-to-nearest-even
    return (unsigned short)(u >> 16);
}

// Pack W (f32 [K][64]) -> bf16 tiles of 64 k (8 KB), PERMUTED so that the
// B fragment matches an A layout where lane (fr,kg) holds k = kg*16+[0..15]
// contiguously. Logical k -> tile position: block = ((k>>3)&1)*4 + (k>>4),
// short idx = (block*64 + c)*8 + (k&7). Zero-filled past K.
__global__ __launch_bounds__(256) void pack_w(BagArgs args,
                                              unsigned short* __restrict__ Wp) {
    __shared__ unsigned short ls[4][4096];
    const int wv = threadIdx.x >> 6;
    const int c  = threadIdx.x & 63;
    const int gtile = blockIdx.x * 4 + wv;

    int bag = 0;
#pragma unroll
    for (int b = 1; b < NBAGS; ++b)
        if (gtile >= args.tstart[b]) bag = b;
    const int lt = gtile - args.tstart[bag];
    const float* __restrict__ W = args.W[bag];
    const int K = args.K[bag];

    unsigned short* L = ls[wv];
#pragma unroll 8
    for (int k = 0; k < 64; ++k) {
        const int gk = lt * 64 + k;
        float v = (gk < K) ? W[(size_t)gk * LF + c] : 0.f;
        const int block = ((k >> 3) & 1) * 4 + (k >> 4);
        L[(block * LF + c) * 8 + (k & 7)] = f2bf(v);
    }
    __syncthreads();
    unsigned short* dst = Wp + ((size_t)gtile << 12);
#pragma unroll
    for (int j = 0; j < 8; ++j)
        *(short8*)(dst + c * 8 + j * 512) = *(const short8*)(L + c * 8 + j * 512);
}

// MODE 0: partials to ws (plain stores). MODE 1: atomicAdd into out.
// MODE 2: emergency fallback, unpacked f32 W + atomics. No LDS, no barriers.
template<int MODE>
__global__ __launch_bounds__(256) void bag_gemm(BagArgs args,
                                                const unsigned short* __restrict__ Wp,
                                                float* __restrict__ dstbuf,
                                                float* __restrict__ sums)
{
    const int tid  = threadIdx.x;
    const int wave = tid >> 6;
    const int lane = tid & 63;
    const int fr   = lane & 15;
    const int kg   = lane >> 4;

    const int g  = blockIdx.x >> 4;    // global chunk (bags 1..4)
    const int mt = blockIdx.x & 15;    // m-tile (128 rows)

    int bag = 1;
#pragma unroll
    for (int b = 2; b < NBAGS; ++b)
        if (g >= args.cstart[b]) bag = b;
    const int chunk  = g - args.cstart[bag];
    const int K      = args.K[bag];
    const int kc0    = chunk * KC;
    const int kend   = min(kc0 + KC, K);
    const int ksz    = kend - kc0;
    const int nsuper = (ksz + 63) >> 6;

    const int row0 = mt * MT_BLOCK + wave * 32;
    // lane (fr,kg) reads 64 B contiguous per row per superstep: k = kg*16+[0..15]
    const int* __restrict__ pA0 = args.A[bag] + (size_t)(row0 + fr) * K + kc0 + kg * 16;
    const int* __restrict__ pA1 = pA0 + (size_t)16 * K;
    const unsigned short* __restrict__ pB =
        Wp + ((size_t)(args.tstart[bag] + chunk * (KC / 64)) << 12) + (kg * LF + fr) * 8;
    const float* __restrict__ Wf = args.W[bag];

    f32x4 acc0[4], acc1[4];
#pragma unroll
    for (int i = 0; i < 4; ++i) {
        acc0[i] = (f32x4){0.f, 0.f, 0.f, 0.f};
        acc1[i] = (f32x4){0.f, 0.f, 0.f, 0.f};
    }
    f32x4 accS0 = (f32x4){0.f, 0.f, 0.f, 0.f};
    f32x4 accS1 = (f32x4){0.f, 0.f, 0.f, 0.f};
    const int4 uo = make_int4(0x3F803F80, 0x3F803F80, 0x3F803F80, 0x3F803F80);
    const short8 ones = *(const short8*)&uo;

    auto loadB = [&](int ss, short8 (&y)[2][4]) {
        if constexpr (MODE < 2) {
            const unsigned short* p = pB + (size_t)ss * 4096;
#pragma unroll
            for (int m = 0; m < 2; ++m)
#pragma unroll
                for (int ni = 0; ni < 4; ++ni)
                    y[m][ni] = *(const short8*)(p + m * 2048 + ni * 128);
        } else {
#pragma unroll
            for (int m = 0; m < 2; ++m)
#pragma unroll
                for (int ni = 0; ni < 4; ++ni) {
                    unsigned short t[8];
#pragma unroll
                    for (int j = 0; j < 8; ++j) {
                        const int kq = kc0 + ss * 64 + kg * 16 + m * 8 + j;
                        t[j] = (kq < kend) ? f2bf(Wf[(size_t)kq * LF + ni * 16 + fr]) : 0;
                    }
                    y[m][ni] = *(short8*)t;
                }
        }
    };

    auto compute = [&](const int4 (&x)[8], const short8 (&y)[2][4]) {
        short8 fa[2][2];   // [row-set][m]
#pragma unroll
        for (int rs = 0; rs < 2; ++rs)
#pragma unroll
            for (int m = 0; m < 2; ++m) {
                const int4& a = x[rs * 4 + m * 2];
                const int4& b = x[rs * 4 + m * 2 + 1];
                // ints are exactly {0,1}: (x|y<<16)*0x3F80 = bf16(x)|bf16(y)<<16
                const unsigned q0 = (unsigned)(a.x | (a.y << 16)) * 0x3F80u;
                const unsigned q1 = (unsigned)(a.z | (a.w << 16)) * 0x3F80u;
                const unsigned q2 = (unsigned)(b.x | (b.y << 16)) * 0x3F80u;
                const unsigned q3 = (unsigned)(b.z | (b.w << 16)) * 0x3F80u;
                int4 u = make_int4((int)q0, (int)q1, (int)q2, (int)q3);
                fa[rs][m] = *(short8*)&u;
            }
#pragma unroll
        for (int m = 0; m < 2; ++m) {
            accS0 = __builtin_amdgcn_mfma_f32_16x16x32_bf16(fa[0][m], ones, accS0, 0, 0, 0);
            accS1 = __builtin_amdgcn_mfma_f32_16x16x32_bf16(fa[1][m], ones, accS1, 0, 0, 0);
#pragma unroll
            for (int ni = 0; ni < 4; ++ni) {
                acc0[ni] = __builtin_amdgcn_mfma_f32_16x16x32_bf16(fa[0][m], y[m][ni], acc0[ni], 0, 0, 0);
                acc1[ni] = __builtin_amdgcn_mfma_f32_16x16x32_bf16(fa[1][m], y[m][ni], acc1[ni], 0, 0, 0);
            }
        }
    };

    // ping-pong pipeline (depth 1), templated on whether A loads need masking
    auto pipeline = [&](auto MASKED) {
        auto loadA = [&](int ss, int4 (&x)[8]) {
            if constexpr (decltype(MASKED)::value) {
#pragma unroll
                for (int i = 0; i < 4; ++i) {
                    const int kq = kc0 + ss * 64 + kg * 16 + i * 4;
                    const int kcl = min(kq, kend - 4);       // safe addr (K%4==0)
                    const int d = kcl - kq;
                    int4 v0 = *(const int4*)(pA0 + ss * 64 + i * 4 + d);
                    int4 v1 = *(const int4*)(pA1 + ss * 64 + i * 4 + d);
                    const bool ok = kq < kend;
                    const int4 z = make_int4(0, 0, 0, 0);
                    x[i]     = ok ? v0 : z;
                    x[4 + i] = ok ? v1 : z;
                }
            } else {
                const int* p0 = pA0 + ss * 64;
                const int* p1 = pA1 + ss * 64;
#pragma unroll
                for (int i = 0; i < 4; ++i) {
                    x[i]     = *(const int4*)(p0 + i * 4);
                    x[4 + i] = *(const int4*)(p1 + i * 4);
                }
            }
        };

        int4   Aa[8], Ab[8];
        short8 Ba[2][4], Bb[2][4];
        loadA(0, Aa);
        loadB(0, Ba);
        const int npair = (nsuper + 1) >> 1;
        for (int p = 0; p < npair; ++p) {
            const int s1  = 2 * p + 1;
            const int s1c = min(s1, nsuper - 1);
            loadA(s1c, Ab);
            loadB(s1c, Bb);
            __builtin_amdgcn_sched_barrier(0);
            compute(Aa, Ba);                       // step 2p (always valid)
            const int s2c = min(2 * p + 2, nsuper - 1);
            loadA(s2c, Aa);
            loadB(s2c, Ba);
            __builtin_amdgcn_sched_barrier(0);
            if (s1 < nsuper)                       // uniform pad guard
                compute(Ab, Bb);
        }
    };

    if ((ksz & 63) == 0) pipeline(std::false_type{});
    else                 pipeline(std::true_type{});

    // row popcounts came from the ones-MFMA: lane (fr,kg) reg r = rowsum of
    // row0 + kg*4 + r (all fr identical). Counts are exact in f32.
    if (fr == 0) {
#pragma unroll
        for (int r = 0; r < 4; ++r) {
            atomicAdd(&sums[bag * BROWS + row0 + kg * 4 + r],      accS0[r]);
            atomicAdd(&sums[bag * BROWS + row0 + 16 + kg * 4 + r], accS1[r]);
        }
    }

    // C/D: col = lane&15 (=fr), row = kg*4 + reg   [validated R1-R4]
    if constexpr (MODE == 0) {
        float* dst = dstbuf + ((size_t)g * BROWS + row0 + kg * 4) * LF + fr;
#pragma unroll
        for (int ni = 0; ni < 4; ++ni)
#pragma unroll
            for (int r = 0; r < 4; ++r) {
                dst[(size_t)(r) * LF + ni * 16]      = acc0[ni][r];
                dst[(size_t)(16 + r) * LF + ni * 16] = acc1[ni][r];
            }
    } else {
#pragma unroll
        for (int ni = 0; ni < 4; ++ni)
#pragma unroll
            for (int r = 0; r < 4; ++r) {
                atomicAdd(dstbuf + (size_t)(row0 + kg * 4 + r) * OUTC + bag * LF + ni * 16 + fr,
                          acc0[ni][r]);
                atomicAdd(dstbuf + (size_t)(row0 + 16 + kg * 4 + r) * OUTC + bag * LF + ni * 16 + fr,
                          acc1[ni][r]);
            }
    }
}

// Sum split-K partials (or read accumulated out), apply normalization
// (incl. the faithful "decades divided twice" bug), and compute the tiny
// K=12 decades bag directly in f32.
template<bool FROMPART>
__global__ __launch_bounds__(256) void reduce_norm(BagArgs args,
                                                   const float* __restrict__ part,
                                                   float* __restrict__ out,
                                                   const float* __restrict__ sums)
{
    const int idx = blockIdx.x * 256 + threadIdx.x;
    if (idx >= BROWS * OUTC) return;
    const int row = idx / OUTC;
    const int c   = idx - row * OUTC;
    const int bag = c >> 6;
    const int col = c & 63;

    float v;
    if (bag == 0) {
        const int*   A0 = args.A[0];
        const float* W0 = args.W[0];
        float a = 0.f; int s = 0;
#pragma unroll
        for (int k = 0; k < 12; ++k) {
            const int x = A0[row * 12 + k];
            s += x;
            if (x) a += W0[k * LF + col];
        }
        if (s) a /= (float)s;
        const float sm = sums[1 * BROWS + row];   // ref bug: also divide by movie sum
        if (sm != 0.f) a /= sm;
        v = a;
    } else {
        if constexpr (FROMPART) {
            float a = 0.f;
            for (int gg = args.cstart[bag]; gg < args.cstart[bag + 1]; ++gg)
                a += part[((size_t)gg * BROWS + row) * LF + col];
            v = a;
        } else {
            v = out[idx];
        }
        if (bag >= 2) {
            const float s = sums[bag * BROWS + row];
            if (s != 0.f) v /= s;
        }
        // bag 1 (movies): never normalized (faithful to reference bug)
    }
    out[idx] = v;
}

extern "C" void kernel_launch(void* const* d_in, const int* in_sizes, int n_in,
                              void* d_out, int out_size, void* d_ws, size_t ws_size,
                              hipStream_t stream) {
    float* out = (float*)d_out;
    float* sums = (float*)d_ws;
    unsigned short* Wp = (unsigned short*)((char*)d_ws + WS_SUMS_BYTES);
    float* part = (float*)((char*)d_ws + PART_OFF);

    BagArgs args;
    const int Ks[NBAGS] = {12, 60000, 32, 100000, 20000};
    int tcum = 0;
    for (int b = 0; b < NBAGS; ++b) {
        args.A[b] = (const int*)d_in[b];
        args.W[b] = (const float*)d_in[5 + b];
        args.K[b] = Ks[b];
        args.tstart[b] = tcum;
        tcum += (Ks[b] + 63) / 64;          // -> 2816
    }
    args.tstart[NBAGS] = tcum;
    args.cstart[0] = 0;
    int ccum = 0;
    for (int b = 1; b < NBAGS; ++b) {
        args.cstart[b] = ccum;
        ccum += (Ks[b] + KC - 1) / KC;      // 30 + 1 + 49 + 10 = 90
    }
    args.cstart[NBAGS] = ccum;

    hipMemsetAsync(sums, 0, NBAGS * BROWS * sizeof(float), stream);

    const bool have_wp   = ws_size >= (size_t)WS_SUMS_BYTES + WP_BYTES;
    const bool have_part = ws_size >= PART_OFF + PART_BYTES;

    if (have_wp)
        pack_w<<<tcum / 4, 256, 0, stream>>>(args, Wp);

    dim3 grid(NCHUNKS * NMT);
    if (have_wp && have_part) {
        bag_gemm<0><<<grid, 256, 0, stream>>>(args, Wp, part, sums);
        reduce_norm<true><<<(BROWS * OUTC + 255) / 256, 256, 0, stream>>>(args, part, out, sums);
    } else if (have_wp) {
        hipMemsetAsync(d_out, 0, (size_t)out_size * sizeof(float), stream);
        bag_gemm<1><<<grid, 256, 0, stream>>>(args, Wp, out, sums);
        reduce_norm<false><<<(BROWS * OUTC + 255) / 256, 256, 0, stream>>>(args, part, out, sums);
    } else {
        hipMemsetAsync(d_out, 0, (size_t)out_size * sizeof(float), stream);
        bag_gemm<2><<<grid, 256, 0, stream>>>(args, Wp, out, sums);
        reduce_norm<false><<<(BROWS * OUTC + 255) / 256, 256, 0, stream>>>(args, part, out, sums);
    }
}